// Round 10
// baseline (218.902 us; speedup 1.0000x reference)
//
#include <hip/hip_runtime.h>
#include <stdint.h>

#define NA 98304
#define NT 1024
#define NC 21
#define NBUCK 1536           // 16x16 spatial cells x (2 width x 3 height) size classes
#define CAP 128              // slots/bucket (Poisson mean 64; overflow -> exact spill)
#define HI_MIN 0xBF000000u   // min high-word of a valid key (iou>=0.5, bias bit)
#define C3S 0.33333f         // (1/3)*(1-1e-5): conservative screen scale (superset)

typedef unsigned int u32;
typedef unsigned long long u64;

// ws layout (memset covers [0, 8192)):
//   [0]       int   done2
//   [4]       int   spillcnt
//   [128]     int   done_g[64]
//   [1024]    int   cursor[1536]      6 KB (zeroed)
//   [8192]    float part[1536]        6 KB (unique-slot)
//   [16384]   int   npos_part[1536]   6 KB (unique-slot)
//   [24576]   u64   tkeys[1024]       8 KB (NOT zeroed: poison-proof, idempotent)
//   [32768]   f4    sortedA[1536*128] 3 MB (guarded by cursor counts)
//   [3178496] u32   sortedId[1536*128] 768 KB
//   [3964928] f4    spillA[98304]     1.5 MB (normally untouched)
//   [5537792] u32   spillId[98304]    384 KB
// total ~5.9 MB (R9 used 7.3 MB successfully)

__device__ __forceinline__ float f0(float x) {   // focal, target=0
    const float ax = fabsf(x);
    const float u  = __expf(-ax);
    const float ce = fmaxf(x, 0.f) + __logf(1.f + u);
    const float p  = (x >= 0.f ? 1.f : u) / (1.f + u);
    return 0.75f * p * p * ce;
}
__device__ __forceinline__ float f1(float x) {   // focal, target=1
    const float ax = fabsf(x);
    const float u  = __expf(-ax);
    const float ce = fmaxf(x, 0.f) - x + __logf(1.f + u);
    const float p  = (x >= 0.f ? 1.f : u) / (1.f + u);
    const float q  = 1.f - p;
    return 0.25f * q * q * ce;
}
__device__ __forceinline__ u64 mk_key(float iou, u32 idx) {
    // bias bit beats 0xAA-poison/0 under unsigned max; iou order preserved;
    // low word 0xFFFFFFFF-idx -> smaller index wins ties (matches argmax).
    return ((u64)(__float_as_uint(iou) | 0x80000000u) << 32) |
           (u64)(0xFFFFFFFFu - idx);
}
__device__ __forceinline__ float smooth_l1(float d) {
    const float ad = fabsf(d);
    return (ad < 1.f) ? 0.5f * d * d : ad - 0.5f;
}
__device__ __forceinline__ u64 aload64(const u64* p) {
    return __hip_atomic_load(p, __ATOMIC_RELAXED, __HIP_MEMORY_SCOPE_AGENT);
}
__device__ __forceinline__ float aloadf(const float* p) {
    return __hip_atomic_load(p, __ATOMIC_RELAXED, __HIP_MEMORY_SCOPE_AGENT);
}
__device__ __forceinline__ int aloadi(const int* p) {
    return __hip_atomic_load(p, __ATOMIC_RELAXED, __HIP_MEMORY_SCOPE_AGENT);
}
__device__ __forceinline__ int iclamp(int v, int lo, int hi) {
    return v < lo ? lo : (v > hi ? hi : v);
}

// ================= kernel 1: bucket-scatter anchors ==========================
__global__ __launch_bounds__(256) void k_scatter(
    const float4* __restrict__ anchors,
    float4* __restrict__ sortedA, u32* __restrict__ sortedId,
    int* __restrict__ cursor, int* __restrict__ spillcnt,
    float4* __restrict__ spillA, u32* __restrict__ spillId)
{
    const int a = blockIdx.x * 256 + threadIdx.x;   // 384 x 256 = 98304 exact
    const float4 A = anchors[a];
    const float acx = (A.x + A.z) * 0.5f, acy = (A.y + A.w) * 0.5f;
    const float aw  = A.z - A.x,          ah  = A.w - A.y;
    const int cx = iclamp((int)((acx - 0.15f) * 22.857143f), 0, 15);
    const int cy = iclamp((int)((acy - 0.15f) * 22.857143f), 0, 15);
    const int wc = iclamp((int)((aw - 0.05f) * 8.0f),  0, 1);
    const int hc = iclamp((int)((ah - 0.05f) * 12.0f), 0, 2);
    const int bkt = cx + (cy << 4) + ((wc + hc * 2) << 8);   // [0,1536)
    const int pos = atomicAdd(&cursor[bkt], 1);
    if (pos < CAP) {
        sortedA[bkt * CAP + pos]  = A;
        sortedId[bkt * CAP + pos] = (u32)a;
    } else {   // overflow: exact slow path in final block (normally empty)
        const int sp = atomicAdd(spillcnt, 1);
        spillA[sp]  = A;
        spillId[sp] = (u32)a;
    }
}

// Screen+hit for one lane-register anchor slot vs the shfl-broadcast target t.
// Screen fma(w,h0,narc)>=sac <=> w*h0 >= (ar+sa)*C3S (R3/R7-proven superset;
// sentinel narc=-1e30 never passes). Hit: exact IEEE fp32 IoU, bit-identical
// to reference (negations exact); keys commutative-idempotent atomicMax.
#define SLOT(az_, nax_, aw_, nay_, narc_, aid_, bk_)                        \
    {                                                                       \
        const float w0 = fminf(az_, u_tz) + fminf(nax_, u_ntx);             \
        const float w  = fmaxf(w0, 0.f);                                    \
        const float h0 = fminf(aw_, u_tw) + fminf(nay_, u_nty);             \
        if (fmaf(w, h0, narc_) >= u_sac) {                                  \
            const float h     = fmaxf(h0, 0.f);                             \
            const float inter = w * h;                                      \
            const float ar    = (az_ + nax_) * (aw_ + nay_);                \
            const float sa    = (u_tz + u_ntx) * (u_tw + u_nty);            \
            const float uni   = (ar + sa) - inter;                          \
            const float iou   = inter / uni;                                \
            const u64 nk = mk_key(iou, (u32)t);                             \
            if (nk > bk_) bk_ = nk;                                         \
            atomicMax(&tkeys[t], mk_key(iou, aid_));                        \
        }                                                                   \
    }

// ================= kernel 2: main ===========================================
__global__ __launch_bounds__(256) void k_main(
    const float* __restrict__ preds,
    const float4* __restrict__ preds4,
    const int* __restrict__ tlabels,
    const float4* __restrict__ anchors,
    const float4* __restrict__ tboxes,
    const float4* __restrict__ bpreds,
    const float4* __restrict__ sortedA, const u32* __restrict__ sortedId,
    const int* __restrict__ cursor, const int* __restrict__ spillcnt,
    const float4* __restrict__ spillA, const u32* __restrict__ spillId,
    u64* __restrict__ tkeys,
    float* __restrict__ part, int* __restrict__ npos_part,
    int* __restrict__ done_g, int* __restrict__ done2,
    float* __restrict__ out)
{
    __shared__ u64    s_bk[4][CAP];   // per-wave anchor best keys (4 KB)
    __shared__ float  s_f[4];
    __shared__ float  s_a[2];
    __shared__ int    s_c[2];
    __shared__ int    s_fin;
    __shared__ u64    s_sp[4];
    __shared__ double s_d[4];
    __shared__ int    s_i[4];
    __shared__ float  s_s[4], s_m[4];

    const int tid  = threadIdx.x;
    const int b    = blockIdx.x;
    const int lane = tid & 63, wid = tid >> 6;
    const int cnt0 = cursor[b];
    const int cnt  = cnt0 > CAP ? CAP : cnt0;

    // -------- stage lane's 2 anchor slots (register-resident; sentinel-safe) -
    const bool v1 = lane < cnt;
    const bool v2 = lane + 64 < cnt;
    float4 A1 = make_float4(1e30f, 1e30f, -1e30f, -1e30f);
    float4 A2 = A1;
    u32 aid1 = 0u, aid2 = 0u;
    if (v1) { A1 = sortedA[b * CAP + lane];      aid1 = sortedId[b * CAP + lane]; }
    if (v2) { A2 = sortedA[b * CAP + 64 + lane]; aid2 = sortedId[b * CAP + 64 + lane]; }
    const float nax1 = -A1.x, nay1 = -A1.y, az1 = A1.z, aw1 = A1.w;
    const float nax2 = -A2.x, nay2 = -A2.y, az2 = A2.z, aw2 = A2.w;
    const float narc1 = v1 ? -(((A1.z - A1.x) * (A1.w - A1.y)) * C3S) : -1e30f;
    const float narc2 = v2 ? -(((A2.z - A2.x) * (A2.w - A2.y)) * C3S) : -1e30f;

    // -------- lane's 4 targets in registers (coalesced loads) ----------------
    float ntx[4], nty[4], tzz[4], tww[4], sac[4];
    #pragma unroll
    for (int r = 0; r < 4; ++r) {
        const float4 tb = tboxes[wid * 256 + 64 * r + lane];
        ntx[r] = -tb.x; nty[r] = -tb.y; tzz[r] = tb.z; tww[r] = tb.w;
        sac[r] = ((tb.z - tb.x) * (tb.w - tb.y)) * C3S;
    }

    // f0 over this block's contiguous 336-float4 slice of preds
    float facc;
    {
        const int pb = b * 336;
        const float4 v0 = preds4[pb + tid];
        facc = (f0(v0.x) + f0(v0.y)) + (f0(v0.z) + f0(v0.w));
        if (tid < 80) {
            const float4 vv = preds4[pb + 256 + tid];
            facc += (f0(vv.x) + f0(vv.y)) + (f0(vv.z) + f0(vv.w));
        }
    }

    // -------- per-wave block bbox + size maxima (shfl reduce, no barrier) ----
    const float cx1 = (A1.x + A1.z) * 0.5f, cy1 = (A1.y + A1.w) * 0.5f;
    const float cx2 = (A2.x + A2.z) * 0.5f, cy2 = (A2.y + A2.w) * 0.5f;
    float bxl = fminf(v1 ? cx1 :  1e30f, v2 ? cx2 :  1e30f);
    float bxh = fmaxf(v1 ? cx1 : -1e30f, v2 ? cx2 : -1e30f);
    float byl = fminf(v1 ? cy1 :  1e30f, v2 ? cy2 :  1e30f);
    float byh = fmaxf(v1 ? cy1 : -1e30f, v2 ? cy2 : -1e30f);
    float awm = fmaxf(v1 ? (A1.z - A1.x) : 0.f, v2 ? (A2.z - A2.x) : 0.f);
    float ahm = fmaxf(v1 ? (A1.w - A1.y) : 0.f, v2 ? (A2.w - A2.y) : 0.f);
    for (int o = 32; o > 0; o >>= 1) {
        bxl = fminf(bxl, __shfl_xor(bxl, o));
        bxh = fmaxf(bxh, __shfl_xor(bxh, o));
        byl = fminf(byl, __shfl_xor(byl, o));
        byh = fmaxf(byh, __shfl_xor(byh, o));
        awm = fmaxf(awm, __shfl_xor(awm, o));
        ahm = fmaxf(ahm, __shfl_xor(ahm, o));
    }

    // -------- hot loop: ballot-prescreen + shfl-gather candidate walk --------
    // Window (R9 harness-proven): match => |acx-tcx| <= (aw+tw)/2-max(aw,tw)/3,
    // monotone in aw -> awm bound valid; +1e-3 margin >> fp slop. bbox/awm are
    // DATA-derived -> correct for any input regardless of binning. Empty
    // bucket: bxl=+1e30 -> cand==0. Zero LDS, zero barriers in this loop.
    u64 bk1 = 0ull, bk2 = 0ull;
    const int tb0 = wid * 256;
    #pragma unroll
    for (int r = 0; r < 4; ++r) {
        const float twd = tzz[r] + ntx[r];              // tz - tx (exact)
        const float thd = tww[r] + nty[r];
        const float tcx = (tzz[r] - ntx[r]) * 0.5f;     // (tx + tz)/2 (exact)
        const float tcy = (tww[r] - nty[r]) * 0.5f;
        const float rx = (awm + twd) * 0.5f - fmaxf(awm, twd) * (1.f/3.f) + 1e-3f;
        const float ry = (ahm + thd) * 0.5f - fmaxf(ahm, thd) * (1.f/3.f) + 1e-3f;
        const bool inw = (tcx >= bxl - rx) && (tcx <= bxh + rx) &&
                         (tcy >= byl - ry) && (tcy <= byh + ry);
        u64 cand = __ballot(inw);
        while (cand != 0ull) {
            const int src = __ffsll(cand) - 1;
            cand &= cand - 1;
            const float u_ntx = __shfl(ntx[r], src);
            const float u_nty = __shfl(nty[r], src);
            const float u_tz  = __shfl(tzz[r], src);
            const float u_tw  = __shfl(tww[r], src);
            const float u_sac = __shfl(sac[r], src);
            const int   t     = tb0 + 64 * r + src;
            SLOT(az1, nax1, aw1, nay1, narc1, aid1, bk1)
            SLOT(az2, nax2, aw2, nay2, narc2, aid2, bk2)
        }
    }

    // -------- per-wave anchor keys to LDS + f0 reduce ------------------------
    s_bk[wid][lane]      = bk1;
    s_bk[wid][64 + lane] = bk2;
    for (int o = 32; o > 0; o >>= 1) facc += __shfl_down(facc, o);
    if (lane == 0) s_f[wid] = facc;
    __syncthreads();

    // -------- anchor finalize: npos + (f1-f0) correction (2 waves) -----------
    if (tid < CAP) {
        u64 k0 = s_bk[0][tid];
        const u64 k1 = s_bk[1][tid], k2 = s_bk[2][tid], k3 = s_bk[3][tid];
        if (k1 > k0) k0 = k1;
        if (k2 > k0) k0 = k2;
        if (k3 > k0) k0 = k3;
        float corrv = 0.f;
        int   c2    = 0;
        if ((u32)(k0 >> 32) >= HI_MIN) {   // max IoU >= 0.5f exactly
            c2 = 1;
            const int tI  = (int)(0xFFFFFFFFu - (u32)k0);
            const int lab = tlabels[tI];
            const u32 aid = sortedId[b * CAP + tid];
            const float x = preds[aid * NC + lab];
            corrv = f1(x) - f0(x);
        }
        for (int o = 32; o > 0; o >>= 1) {
            corrv += __shfl_down(corrv, o);
            c2    += __shfl_down(c2, o);
        }
        if (lane == 0) { s_a[wid] = corrv; s_c[wid] = c2; }
    }
    __syncthreads();
    if (tid == 0) {
        __hip_atomic_store(&part[b],
            (s_f[0] + s_f[1] + s_f[2] + s_f[3]) + s_a[0] + s_a[1],
            __ATOMIC_RELAXED, __HIP_MEMORY_SCOPE_AGENT);
        __hip_atomic_store(&npos_part[b], s_c[0] + s_c[1],
            __ATOMIC_RELAXED, __HIP_MEMORY_SCOPE_AGENT);
    }
    __syncthreads();   // drains each wave's tkeys atomics (vmcnt) before bump
    // -------- 2-level completion: 64 group counters (24 each) -> done2 (64) --
    if (tid == 0) {
        __threadfence();
        int fin = 0;
        if (atomicAdd(&done_g[b & 63], 1) == 23) {
            __threadfence();
            fin = (atomicAdd(done2, 1) == 63);
        }
        s_fin = fin;
    }
    __syncthreads();
    if (!s_fin) return;
    __builtin_amdgcn_fence(__ATOMIC_ACQUIRE, "agent");   // L1 invalidate

    // ============ FINAL (last completer) ====================================
    double cl = 0.0;
    int    np = 0;
    #pragma unroll
    for (int j = 0; j < 6; ++j) {
        const int i = tid + 256 * j;
        cl += (double)aloadf(&part[i]);
        np += aloadi(&npos_part[i]);
    }

    // ---- exact slow path for spilled anchors (normally sc == 0) -------------
    const int sc0 = aloadi(spillcnt);
    const int sc  = sc0 > NA ? NA : sc0;
    for (int a = 0; a < sc; ++a) {
        const float4 A = spillA[a];
        const u32 aid  = spillId[a];
        const float ar = (A.z - A.x) * (A.w - A.y);
        u64 bk = 0ull;
        #pragma unroll
        for (int k = 0; k < 4; ++k) {
            const int t = tid + 256 * k;
            const float4 tb = tboxes[t];
            const float sa = (tb.z - tb.x) * (tb.w - tb.y);
            const float w = fmaxf(fminf(A.z, tb.z) - fmaxf(A.x, tb.x), 0.f);
            const float h = fmaxf(fminf(A.w, tb.w) - fmaxf(A.y, tb.y), 0.f);
            const float inter = w * h;
            const float uni   = (ar + sa) - inter;
            const float iou   = inter / uni;
            if (iou >= 0.5f) {
                const u64 nk = mk_key(iou, (u32)t);
                if (nk > bk) bk = nk;
                atomicMax(&tkeys[t], mk_key(iou, aid));
            }
        }
        for (int o = 32; o > 0; o >>= 1) {
            const u64 ob = __shfl_down(bk, o);
            if (ob > bk) bk = ob;
        }
        if (lane == 0) s_sp[wid] = bk;
        __syncthreads();
        if (tid == 0) {
            u64 k0 = s_sp[0];
            if (s_sp[1] > k0) k0 = s_sp[1];
            if (s_sp[2] > k0) k0 = s_sp[2];
            if (s_sp[3] > k0) k0 = s_sp[3];
            if ((u32)(k0 >> 32) >= HI_MIN) {
                np += 1;
                const int tI  = (int)(0xFFFFFFFFu - (u32)k0);
                const int lab = tlabels[tI];
                const float x = preds[aid * NC + lab];
                cl += (double)(f1(x) - f0(x));
            }
        }
        __syncthreads();
    }

    // ---- regression over matched targets ------------------------------------
    float s = 0.f, m = 0.f;
    #pragma unroll
    for (int j = 0; j < 4; ++j) {
        const int t = tid + 256 * j;
        const u64 key = aload64(&tkeys[t]);
        if ((u32)(key >> 32) >= HI_MIN) {
            const u32 ga = 0xFFFFFFFFu - (u32)key;
            const float4 tb  = tboxes[t];
            const float4 abx = anchors[ga];
            const float4 pb  = bpreds[ga];
            const float bw = tb.z - tb.x, bh = tb.w - tb.y;
            const float bcx = tb.x + 0.5f * bw, bcy = tb.y + 0.5f * bh;
            const float aw = abx.z - abx.x, ah = abx.w - abx.y;
            const float acx = abx.x + 0.5f * aw, acy = abx.y + 0.5f * ah;
            const float tx = (bcx - acx) / aw;
            const float ty = (bcy - acy) / ah;
            const float tw = logf(fmaxf(bw, 1e-8f) / aw);
            const float th = logf(fmaxf(bh, 1e-8f) / ah);
            s += smooth_l1(pb.x - tx) + smooth_l1(pb.y - ty) +
                 smooth_l1(pb.z - tw) + smooth_l1(pb.w - th);
            m += 1.f;
        }
    }
    for (int o = 32; o > 0; o >>= 1) {
        cl += __shfl_down(cl, o);
        np += __shfl_down(np, o);
        s  += __shfl_down(s, o);
        m  += __shfl_down(m, o);
    }
    __syncthreads();
    if (lane == 0) { s_d[wid] = cl; s_i[wid] = np; s_s[wid] = s; s_m[wid] = m; }
    __syncthreads();
    if (tid == 0) {
        const double cls_sum = s_d[0] + s_d[1] + s_d[2] + s_d[3];
        const int    npos    = s_i[0] + s_i[1] + s_i[2] + s_i[3];
        const float  rs      = s_s[0] + s_s[1] + s_s[2] + s_s[3];
        const float  rm      = s_m[0] + s_m[1] + s_m[2] + s_m[3];
        const float cls = (float)(cls_sum / (double)npos);
        const float reg = rs / (fmaxf(rm, 1.f) * 4.f);
        out[0] = cls + reg;
        out[1] = cls;
        out[2] = reg;
    }
}

extern "C" void kernel_launch(void* const* d_in, const int* in_sizes, int n_in,
                              void* d_out, int out_size, void* d_ws, size_t ws_size,
                              hipStream_t stream) {
    const float*  preds   = (const float*)d_in[0];
    const float4* preds4  = (const float4*)d_in[0];
    const float4* bpreds  = (const float4*)d_in[1];
    const float4* anchors = (const float4*)d_in[2];
    const float4* tboxes  = (const float4*)d_in[3];
    const int*    tlabels = (const int*)d_in[4];

    char* ws = (char*)d_ws;
    int*    done2     = (int*)(ws + 0);
    int*    spillcnt  = (int*)(ws + 4);
    int*    done_g    = (int*)(ws + 128);
    int*    cursor    = (int*)(ws + 1024);
    float*  part      = (float*)(ws + 8192);
    int*    npos_part = (int*)(ws + 16384);
    u64*    tkeys     = (u64*)(ws + 24576);
    float4* sortedA   = (float4*)(ws + 32768);
    u32*    sortedId  = (u32*)(ws + 3178496);
    float4* spillA    = (float4*)(ws + 3964928);
    u32*    spillId   = (u32*)(ws + 5537792);

    // zero: done counters + spillcnt + cursor (parts unique-slot, tkeys poison-proof)
    hipMemsetAsync(d_ws, 0, 8192, stream);

    k_scatter<<<dim3(384), 256, 0, stream>>>(
        anchors, sortedA, sortedId, cursor, spillcnt, spillA, spillId);

    k_main<<<dim3(NBUCK), 256, 0, stream>>>(
        preds, preds4, tlabels, anchors, tboxes, bpreds,
        sortedA, sortedId, cursor, spillcnt, spillA, spillId,
        tkeys, part, npos_part, done_g, done2, (float*)d_out);
}

// Round 11
// 124.768 us; speedup vs baseline: 1.7545x; 1.7545x over previous
//
#include <hip/hip_runtime.h>
#include <stdint.h>

#define NA 98304
#define NT 1024
#define NC 21
#define NBLK 1536            // one block per 64 anchors; each block sees ALL targets
#define HI_MIN 0xBF000000u   // min high-word of a valid key (iou>=0.5, bias bit)
#define C3S 0.33333f         // (1/3)*(1-1e-5): conservative screen scale (superset)

typedef unsigned int u32;
typedef unsigned long long u64;

// ws layout:
//   [0]      int   done2            (zeroed by memset)
//   [128]    int   done_g[64]       (256 B, zeroed by memset)
//   [1024]   float part[NBLK]       (6 KB, unique-slot stores: f0 sum + f1-f0 corr)
//   [8192]   int   npos_part[NBLK]  (6 KB, unique-slot)
//   [16384]  u64   tkeys[NT]        (8 KB, NOT zeroed: poison-proof keys, idempotent)
// memset covers only [0, 1024)

__device__ __forceinline__ float f0(float x) {   // focal, target=0
    const float ax = fabsf(x);
    const float u  = __expf(-ax);
    const float ce = fmaxf(x, 0.f) + __logf(1.f + u);
    const float p  = (x >= 0.f ? 1.f : u) / (1.f + u);
    return 0.75f * p * p * ce;
}
__device__ __forceinline__ float f1(float x) {   // focal, target=1
    const float ax = fabsf(x);
    const float u  = __expf(-ax);
    const float ce = fmaxf(x, 0.f) - x + __logf(1.f + u);
    const float p  = (x >= 0.f ? 1.f : u) / (1.f + u);
    const float q  = 1.f - p;
    return 0.25f * q * q * ce;
}
__device__ __forceinline__ u64 mk_key(float iou, u32 idx) {
    // bias bit: valid keys beat 0xAA-poison and 0 under unsigned max;
    // iou ordering preserved; low word 0xFFFFFFFF-idx -> smaller index wins ties.
    return ((u64)(__float_as_uint(iou) | 0x80000000u) << 32) |
           (u64)(0xFFFFFFFFu - idx);
}
__device__ __forceinline__ float smooth_l1(float d) {
    const float ad = fabsf(d);
    return (ad < 1.f) ? 0.5f * d * d : ad - 0.5f;
}
__device__ __forceinline__ u64 aload64(const u64* p) {
    return __hip_atomic_load(p, __ATOMIC_RELAXED, __HIP_MEMORY_SCOPE_AGENT);
}
__device__ __forceinline__ float aloadf(const float* p) {
    return __hip_atomic_load(p, __ATOMIC_RELAXED, __HIP_MEMORY_SCOPE_AGENT);
}
__device__ __forceinline__ int aloadi(const int* p) {
    return __hip_atomic_load(p, __ATOMIC_RELAXED, __HIP_MEMORY_SCOPE_AGENT);
}

// ---- pass 1 (branchless): bit i set iff pair MIGHT have iou>=0.5 ------------
// Screen: fma(w, h0, -ar*C3S) >= sa*C3S  <=>  w*h0 >= (ar+sa)*C3S.
// sac>0 and w>=0, so h0<0 -> lhs<=0 < sac -> false (no clamp needed on h0).
// C3S slack 1e-5 (~84 ulp) >> ~2 ulp fp32 rounding -> strict superset of exact
// fp32 iou>=0.5f. Exact recheck in WALK. Masks in NAMED u64 scalars (never an
// array: R6 showed partial unroll sends runtime-indexed arrays to scratch).
#define SCREEN(j, m)                                                        \
    {                                                                       \
        const float w0 = fminf(az4[j], tb.z) + fminf(negax[j], tb.x);       \
        const float w  = fmaxf(w0, 0.f);                                    \
        const float h0 = fminf(aw4[j], tb.w) + fminf(negay[j], tb.y);       \
        m |= (fmaf(w, h0, -ar34[j]) >= sac) ? (1ull << i) : 0ull;           \
    }

// ---- pass 2: walk rare set bits; exact IEEE fp32 IoU (reference rounding) --
#define WALK(j, mj, bk)                                                     \
    if (mj != 0ull) {                                                       \
        u64 m = mj;                                                         \
        const float arj = (az4[j] + negax[j]) * (aw4[j] + negay[j]);        \
        do {                                                                \
            const int i = __ffsll(m) - 1;                                   \
            m &= m - 1;                                                     \
            const int t = tb0 + 4 * i;                                      \
            const float4 tb = s_t[t];                                       \
            const float sa = (tb.z + tb.x) * (tb.w + tb.y);                 \
            const float w = fmaxf(fminf(az4[j], tb.z) + fminf(negax[j], tb.x), 0.f); \
            const float h = fmaxf(fminf(aw4[j], tb.w) + fminf(negay[j], tb.y), 0.f); \
            const float inter = w * h;                                      \
            const float uni   = (arj + sa) - inter;                         \
            const float iou   = inter / uni;                                \
            const u64 ak = mk_key(iou, (u32)t);                             \
            if (ak > bk) bk = ak;                                           \
            atomicMax(&s_tk[t], mk_key(iou, (u32)(abase + j)));             \
        } while (m != 0ull);                                                \
    }

#define FOLD(bk)                                                            \
    {                                                                       \
        u64 o_ = __shfl_xor(bk, 16);                                        \
        if (o_ > bk) bk = o_;                                               \
        o_ = __shfl_xor(bk, 32);                                            \
        if (o_ > bk) bk = o_;                                               \
    }

__global__ __launch_bounds__(256) void k_all(
    const float* __restrict__ preds,
    const float4* __restrict__ preds4,
    const int* __restrict__ tlabels,
    const float4* __restrict__ anchors,
    const float4* __restrict__ tboxes,
    const float4* __restrict__ bpreds,
    u64* __restrict__ tkeys,
    float* __restrict__ part,
    int* __restrict__ npos_part,
    int* __restrict__ done_g,
    int* __restrict__ done2,
    float* __restrict__ out)
{
    __shared__ float4 s_t[NT];                    // (-x, -y, z, w) per target
    __shared__ u64 s_tk[NT];                      // per-block target best keys
    __shared__ u64 s_bk[4][64];                   // per-wave anchor best keys
    __shared__ float  s_f[4];
    __shared__ int    s_fin;
    __shared__ double s_d[4];
    __shared__ int    s_i[4];
    __shared__ float  s_s[4], s_m[4];

    const int tid  = threadIdx.x;
    const int b    = blockIdx.x;
    const int lane = tid & 63, wid = tid >> 6;

    // -------- stage ALL 1024 targets (issue loads first, overlap with f0) ----
    float4 tbl[4];
    #pragma unroll
    for (int k = 0; k < 4; ++k) tbl[k] = tboxes[tid + 256 * k];

    // f0 over this block's contiguous 336-float4 slice of preds
    float facc;
    {
        const int pb = b * 336;
        const float4 v0 = preds4[pb + tid];
        facc = (f0(v0.x) + f0(v0.y)) + (f0(v0.z) + f0(v0.w));
        if (tid < 80) {
            const float4 v1 = preds4[pb + 256 + tid];
            facc += (f0(v1.x) + f0(v1.y)) + (f0(v1.z) + f0(v1.w));
        }
    }

    #pragma unroll
    for (int k = 0; k < 4; ++k) {
        s_t[tid + 256 * k]  = make_float4(-tbl[k].x, -tbl[k].y, tbl[k].z, tbl[k].w);
        s_tk[tid + 256 * k] = 0ull;
    }

    // -------- 4 anchors per lane: lane = (sl<<4)|qd; anchors abase..abase+3 ---
    const int qd    = lane & 15;     // anchor quad within the block's 64
    const int sl    = lane >> 4;     // target sub-slice (interleave by 4)
    const int abase = b * 64 + 4 * qd;
    float negax[4], negay[4], az4[4], aw4[4], ar34[4];
    #pragma unroll
    for (int j = 0; j < 4; ++j) {
        const float4 A = anchors[abase + j];
        negax[j] = -A.x; negay[j] = -A.y;
        az4[j]   = A.z;  aw4[j]   = A.w;
        ar34[j]  = ((A.z - A.x) * (A.w - A.y)) * C3S;
    }
    __syncthreads();

    // -------- pass 1: branchless hit-mask build over this lane's 64 targets --
    // lane's slice: t = wid*256 + sl + 4*i -> 4 consecutive 16B LDS lines per
    // instr (distinct banks), 16 lanes broadcast each. unroll 16 + VGPR~64 is
    // the empirically best schedule (R3/R7: 64-65 us; all alternatives worse).
    u64 m0 = 0ull, m1 = 0ull, m2 = 0ull, m3 = 0ull;
    const int tb0 = wid * 256 + sl;
    #pragma unroll 16
    for (int i = 0; i < 64; ++i) {
        const float4 tb = s_t[tb0 + 4 * i];
        const float sa  = (tb.z + tb.x) * (tb.w + tb.y);   // exact target area
        const float sac = sa * C3S;
        SCREEN(0, m0)
        SCREEN(1, m1)
        SCREEN(2, m2)
        SCREEN(3, m3)
    }

    // -------- pass 2: rare bit-walk; keys to registers + LDS (no global) -----
    u64 bk0 = 0ull, bk1 = 0ull, bk2 = 0ull, bk3 = 0ull;
    WALK(0, m0, bk0)
    WALK(1, m1, bk1)
    WALK(2, m2, bk2)
    WALK(3, m3, bk3)

    // fold the 4 target-sub-slices (lanes qd, qd+16, qd+32, qd+48)
    FOLD(bk0) FOLD(bk1) FOLD(bk2) FOLD(bk3)
    if (sl == 0) {
        s_bk[wid][4 * qd + 0] = bk0;
        s_bk[wid][4 * qd + 1] = bk1;
        s_bk[wid][4 * qd + 2] = bk2;
        s_bk[wid][4 * qd + 3] = bk3;
    }

    for (int o = 32; o > 0; o >>= 1) facc += __shfl_down(facc, o);
    if (lane == 0) s_f[wid] = facc;
    __syncthreads();

    // -------- flush target keys: ONE global atomic per matched target --------
    #pragma unroll
    for (int k = 0; k < 4; ++k) {
        const int t = tid + 256 * k;
        const u64 v = s_tk[t];
        if (v != 0ull) atomicMax(&tkeys[t], v);
    }

    // -------- in-block anchor finalize: npos + (f1-f0) correction ------------
    float corrv = 0.f;
    int   cnt   = 0;
    if (tid < 64) {
        u64 k0 = s_bk[0][tid];
        const u64 k1 = s_bk[1][tid];
        const u64 k2 = s_bk[2][tid];
        const u64 k3 = s_bk[3][tid];
        if (k1 > k0) k0 = k1;
        if (k2 > k0) k0 = k2;
        if (k3 > k0) k0 = k3;
        if ((u32)(k0 >> 32) >= HI_MIN) {   // max IoU >= 0.5f exactly
            cnt = 1;
            const int tI  = (int)(0xFFFFFFFFu - (u32)k0);
            const int lab = tlabels[tI];
            const float x = preds[(b * 64 + tid) * NC + lab];
            corrv = f1(x) - f0(x);
        }
        for (int o = 32; o > 0; o >>= 1) {
            corrv += __shfl_down(corrv, o);
            cnt   += __shfl_down(cnt, o);
        }
    }
    if (tid == 0) {
        __hip_atomic_store(&part[b], (s_f[0] + s_f[1] + s_f[2] + s_f[3]) + corrv,
                           __ATOMIC_RELAXED, __HIP_MEMORY_SCOPE_AGENT);
        __hip_atomic_store(&npos_part[b], cnt,
                           __ATOMIC_RELAXED, __HIP_MEMORY_SCOPE_AGENT);
    }
    __syncthreads();   // drains each wave's tkeys flush (vmcnt) before bump
    // -------- 2-level completion: 64 group counters (24 each) -> done2 (64) --
    if (tid == 0) {
        __threadfence();
        int fin = 0;
        if (atomicAdd(&done_g[b & 63], 1) == 23) {
            __threadfence();
            fin = (atomicAdd(done2, 1) == 63);
        }
        s_fin = fin;
    }
    __syncthreads();
    if (!s_fin) return;
    __builtin_amdgcn_fence(__ATOMIC_ACQUIRE, "agent");   // L1 invalidate

    // ============ FINAL (last completer): combine + regression ==============
    double cl = 0.0;
    int    np = 0;
    #pragma unroll
    for (int j = 0; j < 6; ++j) {
        const int i = tid + 256 * j;
        cl += (double)aloadf(&part[i]);
        np += aloadi(&npos_part[i]);
    }
    float s = 0.f, m = 0.f;
    #pragma unroll
    for (int j = 0; j < 4; ++j) {
        const int t = tid + 256 * j;
        const u64 key = aload64(&tkeys[t]);
        if ((u32)(key >> 32) >= HI_MIN) {
            const u32 ga = 0xFFFFFFFFu - (u32)key;
            const float4 tb  = tboxes[t];
            const float4 abx = anchors[ga];
            const float4 pb  = bpreds[ga];
            const float bw = tb.z - tb.x, bh = tb.w - tb.y;
            const float bcx = tb.x + 0.5f * bw, bcy = tb.y + 0.5f * bh;
            const float aw = abx.z - abx.x, ah = abx.w - abx.y;
            const float acx = abx.x + 0.5f * aw, acy = abx.y + 0.5f * ah;
            const float tx = (bcx - acx) / aw;
            const float ty = (bcy - acy) / ah;
            const float tw = logf(fmaxf(bw, 1e-8f) / aw);
            const float th = logf(fmaxf(bh, 1e-8f) / ah);
            s += smooth_l1(pb.x - tx) + smooth_l1(pb.y - ty) +
                 smooth_l1(pb.z - tw) + smooth_l1(pb.w - th);
            m += 1.f;
        }
    }
    for (int o = 32; o > 0; o >>= 1) {
        cl += __shfl_down(cl, o);
        np += __shfl_down(np, o);
        s  += __shfl_down(s, o);
        m  += __shfl_down(m, o);
    }
    __syncthreads();
    if (lane == 0) { s_d[wid] = cl; s_i[wid] = np; s_s[wid] = s; s_m[wid] = m; }
    __syncthreads();
    if (tid == 0) {
        const double cls_sum = s_d[0] + s_d[1] + s_d[2] + s_d[3];
        const int    npos    = s_i[0] + s_i[1] + s_i[2] + s_i[3];
        const float  rs      = s_s[0] + s_s[1] + s_s[2] + s_s[3];
        const float  rm      = s_m[0] + s_m[1] + s_m[2] + s_m[3];
        const float cls = (float)(cls_sum / (double)npos);
        const float reg = rs / (fmaxf(rm, 1.f) * 4.f);
        out[0] = cls + reg;
        out[1] = cls;
        out[2] = reg;
    }
}

extern "C" void kernel_launch(void* const* d_in, const int* in_sizes, int n_in,
                              void* d_out, int out_size, void* d_ws, size_t ws_size,
                              hipStream_t stream) {
    const float*  preds   = (const float*)d_in[0];
    const float4* preds4  = (const float4*)d_in[0];
    const float4* bpreds  = (const float4*)d_in[1];
    const float4* anchors = (const float4*)d_in[2];
    const float4* tboxes  = (const float4*)d_in[3];
    const int*    tlabels = (const int*)d_in[4];

    char* ws = (char*)d_ws;
    int*  done2     = (int*)(ws + 0);
    int*  done_g    = (int*)(ws + 128);
    float* part     = (float*)(ws + 1024);
    int*  npos_part = (int*)(ws + 8192);
    u64*  tkeys     = (u64*)(ws + 16384);

    // only the done counters need zeroing (partials unique-slot, tkeys poison-proof)
    hipMemsetAsync(d_ws, 0, 1024, stream);

    k_all<<<dim3(NBLK), 256, 0, stream>>>(
        preds, preds4, tlabels, anchors, tboxes, bpreds,
        tkeys, part, npos_part, done_g, done2, (float*)d_out);
}